// Round 3
// baseline (5689.230 us; speedup 1.0000x reference)
//
#include <hip/hip_runtime.h>
#include <math.h>

#define GAMMA 0.5f

typedef __bf16 bf16x8 __attribute__((ext_vector_type(8)));
typedef float  f32x4  __attribute__((ext_vector_type(4)));

__device__ __forceinline__ unsigned short f2bf(float f){
  union { float ff; unsigned u; } x; x.ff = f;
  return (unsigned short)((x.u + 0x7fffu + ((x.u >> 16) & 1u)) >> 16);
}

__device__ __forceinline__ float fast_tanh(float v){
  // tanh(v) = 1 - 2/(exp(2v)+1); exp->v_exp_f32, rcp->v_rcp_f32 (~1e-7 rel, fine for bf16)
  float e = __expf(v + v);
  return 1.f - 2.f * __builtin_amdgcn_rcpf(e + 1.f);
}

__device__ __forceinline__ void gload16(const void* g, void* l){
  __builtin_amdgcn_global_load_lds((const __attribute__((address_space(1))) void*)g,
                                   (__attribute__((address_space(3))) void*)l,
                                   16, 0, 0);
}

// Counted vmcnt wait (literal immediates only).
template<int N> __device__ __forceinline__ void waitvm(){
  static_assert(N==0 || N==4 || N==6 || N==8 || N==12, "add literal case");
  if      constexpr (N==0)  asm volatile("s_waitcnt vmcnt(0)"  ::: "memory");
  else if constexpr (N==4)  asm volatile("s_waitcnt vmcnt(4)"  ::: "memory");
  else if constexpr (N==6)  asm volatile("s_waitcnt vmcnt(6)"  ::: "memory");
  else if constexpr (N==8)  asm volatile("s_waitcnt vmcnt(8)"  ::: "memory");
  else if constexpr (N==12) asm volatile("s_waitcnt vmcnt(12)" ::: "memory");
}

// C = A[M,Ktot] * B[N,Ktot]^T (row strides lda/ldb), K-chunk of length K selected
// by blockIdx.z (split-K). Tile BM(M) x BN(N), BK=32, 256 threads = 4 waves 2x2,
// each wave owns WM x WN. acc [WM/16][WN/16] f32x4.
// LDS slot layout (conflict-free, m134 lane-linear pattern): 16B chunk
// (row, kq) lives at slot (row>>4)*64 + kq*16 + (row&15). A wave's fragment
// read for lane l=(quad<<4)|lr is then slot g*64 + l -- 64 consecutive 16B
// chunks, the measured 0-conflict b128 pattern. global_load_lds dest is
// lane-linear (required); the (row,kq) permutation is applied to the GLOBAL
// source address instead (m173 pattern).
// K-loop: D-deep LDS ring + counted-vmcnt pipeline (one raw barrier per
// K-step, loads stay in flight across it; never vmcnt(0) in steady state).
// XCD region swizzle: bid%8 -> XCD; compact RMxRN tile region per XCD.
// MODE 0: F0[idx]=v; F1[idx]=v        MODE 1: U0[idx]=bf16(tanh(v))
// MODE 2: atomicAdd(&F0[idx], GAMMA*vraw)   (bias handled by ln_bf16<1>)
// MODE 3: if(n<nmax) F0[idx]=v
template<int MODE, int BM, int BN, int WM, int WN, int D>
__global__ __launch_bounds__(256, 2)
void gemm_bt(const unsigned short* __restrict__ A,
             const unsigned short* __restrict__ B,
             int K, int lda, int ldb, const float* __restrict__ bias,
             int ldc, int nmax, int RM, int MR, int RN,
             float* __restrict__ F0, float* __restrict__ F1,
             unsigned short* __restrict__ U0)
{
  static_assert(BM / WM == 2 && BN / WN == 2, "4 waves arranged 2x2");
  constexpr int MI = WM / 16;          // acc rows of 16
  constexpr int JN = WN / 16;          // acc cols of 16
  constexpr int L  = BM / 64 + BN / 64;   // global_load_lds per thread per K-step
  const int bid = blockIdx.y * gridDim.x + blockIdx.x;
  const int xcd = bid & 7, kk = bid >> 3;
  const int m0 = ((xcd % MR) * RM + (kk % RM)) * BM;
  const int n0 = ((xcd / MR) * RN + (kk / RM)) * BN;
  const long kz = (long)blockIdx.z * K;   // split-K chunk offset
  A += kz; B += kz;

  const int t = threadIdx.x, w = t >> 6, l = t & 63;
  __shared__ __align__(16) unsigned short lgA[D][BM * 32];
  __shared__ __align__(16) unsigned short lgB[D][BN * 32];
  f32x4 acc[MI][JN];
  #pragma unroll
  for (int i = 0; i < MI; i++)
    #pragma unroll
    for (int j = 0; j < JN; j++) acc[i][j] = (f32x4){0.f, 0.f, 0.f, 0.f};

  const int wm = (w & 1) * WM, wn = (w >> 1) * WN;
  const int lr = l & 15, quad = l >> 4;

  // slot c holds data chunk (row = (c>>6)*16 + (c&15), kq = (c>>4)&3)
#define STAGE(kt, buf) { \
    _Pragma("unroll") \
    for (int j = 0; j < BM / 64; j++) { \
      const int c = j * 256 + t; \
      const int row = ((c >> 6) << 4) | (c & 15), kq = (c >> 4) & 3; \
      gload16(A + (long)(m0 + row) * lda + (kt) + kq * 8, (char*)lgA[(buf)] + c * 16); \
    } \
    _Pragma("unroll") \
    for (int j = 0; j < BN / 64; j++) { \
      const int c = j * 256 + t; \
      const int row = ((c >> 6) << 4) | (c & 15), kq = (c >> 4) & 3; \
      gload16(B + (long)(n0 + row) * ldb + (kt) + kq * 8, (char*)lgB[(buf)] + c * 16); \
    } }

#define COMPUTE(buf) { \
    bf16x8 af[MI], bg[JN]; \
    _Pragma("unroll") \
    for (int i = 0; i < MI; i++) \
      af[i] = *(const bf16x8*)&lgA[(buf)][((((wm >> 4) + i) << 6) + l) * 8]; \
    _Pragma("unroll") \
    for (int j = 0; j < JN; j++) \
      bg[j] = *(const bf16x8*)&lgB[(buf)][((((wn >> 4) + j) << 6) + l) * 8]; \
    _Pragma("unroll") \
    for (int i = 0; i < MI; i++) \
      _Pragma("unroll") \
      for (int j = 0; j < JN; j++) \
        acc[i][j] = __builtin_amdgcn_mfma_f32_16x16x32_bf16(af[i], bg[j], acc[i][j], 0, 0, 0); \
  }

  const int NT = K >> 5;               // K-steps (>= 25 for all call sites)
  // Prologue: stage tiles 0..D-2 (no one reads LDS yet).
  #pragma unroll
  for (int i = 0; i < D - 1; ++i) STAGE(i * 32, i)

  int cur = 0;                          // buffer of tile tt (tt % D)
  for (int tt = 0; tt < NT - (D - 1); ++tt) {
    waitvm<L * (D - 2)>();              // tile tt's loads complete (per-wave)
    __builtin_amdgcn_s_barrier();       // raw barrier: no vmcnt drain
    const int prv = (cur == 0) ? D - 1 : cur - 1;  // == (tt+D-1) % D
    STAGE((tt + D - 1) * 32, prv)       // prefetch D-1 ahead, latency hides under compute
    COMPUTE(cur)
    cur = (cur == D - 1) ? 0 : cur + 1;
  }
  // Tail: D-1 iterations, no more staging, decreasing waits.
  if constexpr (D == 4) {
    waitvm<2 * L>();
    __builtin_amdgcn_s_barrier();
    COMPUTE(cur)
    cur = (cur == D - 1) ? 0 : cur + 1;
  }
  waitvm<L>();
  __builtin_amdgcn_s_barrier();
  COMPUTE(cur)
  cur = (cur == D - 1) ? 0 : cur + 1;
  waitvm<0>();
  __builtin_amdgcn_s_barrier();
  COMPUTE(cur)
#undef STAGE
#undef COMPUTE

  #pragma unroll
  for (int i = 0; i < MI; i++) {
    const int mb = m0 + wm + i * 16 + quad * 4;
    #pragma unroll
    for (int j = 0; j < JN; j++) {
      const int n = n0 + wn + j * 16 + lr;
      float bia = 0.f;
      if (MODE == 3) { if (n < nmax) bia = bias[n]; }
      else if (MODE != 2) { bia = bias[n]; }
      #pragma unroll
      for (int r = 0; r < 4; r++) {
        const long m = mb + r;
        const float v = acc[i][j][r] + bia;
        const long idx = m * (long)ldc + n;
        if (MODE == 0)      { F0[idx] = v; F1[idx] = v; }
        else if (MODE == 1) { U0[idx] = f2bf(fast_tanh(v)); }
        else if (MODE == 2) { atomicAdd(&F0[idx], GAMMA * v); }
        else                { if (n < nmax) F0[idx] = v; }
      }
    }
  }
}

// LayerNorm over rows of 1024 fp32 -> bf16 out. One 256-thread block per row.
// PRE=1 additionally pre-writes the next-state base:
//   h <- (1-GAMMA)*h + GAMMA*(xemb + b2)   (GEMM2 then atomicAdds GAMMA*matmul)
// LN stats are computed on the ORIGINAL h values (loaded before overwrite).
template<int PRE>
__global__ __launch_bounds__(256)
void ln_bf16(float* __restrict__ h, const float* __restrict__ gw,
             const float* __restrict__ gb, unsigned short* __restrict__ o,
             const float* __restrict__ xemb, const float* __restrict__ b2)
{
  const int row = blockIdx.x, t = threadIdx.x;
  const float4 v = ((const float4*)(h + (long)row * 1024))[t];
  float s = v.x + v.y + v.z + v.w;
  float q = v.x * v.x + v.y * v.y + v.z * v.z + v.w * v.w;
  #pragma unroll
  for (int o2 = 32; o2 > 0; o2 >>= 1) { s += __shfl_xor(s, o2); q += __shfl_xor(q, o2); }
  __shared__ float rs[4], rq[4];
  if ((t & 63) == 0) { rs[t >> 6] = s; rq[t >> 6] = q; }
  __syncthreads();
  s = rs[0] + rs[1] + rs[2] + rs[3];
  q = rq[0] + rq[1] + rq[2] + rq[3];
  const float mu  = s * (1.f / 1024.f);
  const float inv = rsqrtf(q * (1.f / 1024.f) - mu * mu + 1e-5f);
  const float4 wv = ((const float4*)gw)[t];
  const float4 bv = ((const float4*)gb)[t];
  ushort4 u;
  u.x = f2bf((v.x - mu) * inv * wv.x + bv.x);
  u.y = f2bf((v.y - mu) * inv * wv.y + bv.y);
  u.z = f2bf((v.z - mu) * inv * wv.z + bv.z);
  u.w = f2bf((v.w - mu) * inv * wv.w + bv.w);
  ((ushort4*)(o + (long)row * 1024))[t] = u;
  if (PRE) {
    const float4 xe = ((const float4*)(xemb + (long)row * 1024))[t];
    const float4 b2v = ((const float4*)b2)[t];
    float4 hp;
    hp.x = (1.f - GAMMA) * v.x + GAMMA * (xe.x + b2v.x);
    hp.y = (1.f - GAMMA) * v.y + GAMMA * (xe.y + b2v.y);
    hp.z = (1.f - GAMMA) * v.z + GAMMA * (xe.z + b2v.z);
    hp.w = (1.f - GAMMA) * v.w + GAMMA * (xe.w + b2v.w);
    ((float4*)(h + (long)row * 1024))[t] = hp;
  }
}

// f32 -> bf16 with zero padding
__global__ __launch_bounds__(256)
void cvt_pad(const float* __restrict__ src, unsigned short* __restrict__ dst,
             int src_rows, int src_cols, int dst_cols)
{
  const int r = blockIdx.y;
  const int c = blockIdx.x * 256 + threadIdx.x;
  if (c >= dst_cols) return;
  unsigned short v = 0;
  if (r < src_rows && c < src_cols) v = f2bf(src[(long)r * src_cols + c]);
  dst[(long)r * dst_cols + c] = v;
}

// h fp32 -> bf16, 4 elems/thread
__global__ __launch_bounds__(256)
void cvt_h(const float* __restrict__ h, unsigned short* __restrict__ o)
{
  const long i = (long)blockIdx.x * 256 + threadIdx.x;
  const float4 v = ((const float4*)h)[i];
  ushort4 u;
  u.x = f2bf(v.x); u.y = f2bf(v.y); u.z = f2bf(v.z); u.w = f2bf(v.w);
  ((ushort4*)o)[i] = u;
}

extern "C" void kernel_launch(void* const* d_in, const int* in_sizes, int n_in,
                              void* d_out, int out_size, void* d_ws, size_t ws_size,
                              hipStream_t stream)
{
  const float* x       = (const float*)d_in[0];
  const float* embed_w = (const float*)d_in[1];
  const float* embed_b = (const float*)d_in[2];
  const float* W1_w    = (const float*)d_in[3];
  const float* W1_b    = (const float*)d_in[4];
  const float* W2_w    = (const float*)d_in[5];
  const float* W2_b    = (const float*)d_in[6];
  const float* norm_w  = (const float*)d_in[7];
  const float* norm_b  = (const float*)d_in[8];
  const float* head_w  = (const float*)d_in[9];
  const float* head_b  = (const float*)d_in[10];
  (void)in_sizes; (void)n_in; (void)out_size; (void)ws_size;

  // Workspace layout (all 256B-aligned)
  char* ws = (char*)d_ws;
  unsigned short* W1b  = (unsigned short*)(ws);              //  8,388,608  W1 bf16   [4096][1024]
  unsigned short* W2b  = (unsigned short*)(ws + 8388608);    //  8,388,608  W2 bf16   [1024][4096]
  unsigned short* xb   = (unsigned short*)(ws + 16777216);   //  6,553,600  x bf16    [4096][800] (K-pad)
  unsigned short* ewb  = (unsigned short*)(ws + 23330816);   //  1,638,400  embW bf16 [1024][800] (K-pad)
  unsigned short* hwb  = (unsigned short*)(ws + 24969216);   //  2,097,152  headW bf16[1024][1024] (row-pad)
  float*          xemb = (float*)(ws + 27066368);            // 16,777,216  x_emb f32 [4096][1024]
  float*          h    = (float*)(ws + 43843584);            // 16,777,216  h f32     [4096][1024]
  unsigned short* hn   = (unsigned short*)(ws + 60620800);   //  8,388,608  ln(h) bf16[4096][1024]
  unsigned short* act  = (unsigned short*)(ws + 69009408);   // 33,554,432  ffn act   [4096][4096]
  unsigned short* hb   = (unsigned short*)(ws + 102563840);  //  8,388,608  h bf16    [4096][1024]
  // total 110,952,448 B

  cvt_pad<<<dim3(4, 4096), 256, 0, stream>>>(W1_w, W1b, 4096, 1024, 1024);
  cvt_pad<<<dim3(16, 1024), 256, 0, stream>>>(W2_w, W2b, 1024, 4096, 4096);
  cvt_pad<<<dim3(4, 4096), 256, 0, stream>>>(x, xb, 4096, 784, 800);
  cvt_pad<<<dim3(4, 1024), 256, 0, stream>>>(embed_w, ewb, 1024, 784, 800);
  cvt_pad<<<dim3(4, 1024), 256, 0, stream>>>(head_w, hwb, 1000, 1024, 1024);

  // x_emb = x @ embed_w^T + embed_b ; h = x_emb
  // 128x128 tiles: M-tiles 32, N-tiles 8 -> regions 4(m)x2(n) of 8x4
  gemm_bt<0, 128, 128, 64, 64, 3><<<dim3(8, 32), 256, 0, stream>>>(
      xb, ewb, 800, 800, 800, embed_b, 1024, 1024, 8, 4, 4, xemb, h, nullptr);

  for (int s = 0; s < 30; s++) {
    // hn = ln(h); h <- 0.5h + 0.5(xemb + b2)   (GEMM2 completes h += 0.5*matmul)
    ln_bf16<1><<<4096, 256, 0, stream>>>(h, norm_w, norm_b, hn, xemb, W2_b);
    // act = tanh(hn @ W1^T + b1): 256x128 tiles, waves 128x64 (42.7 FLOP/LDS-B)
    // M-tiles 16, N-tiles 32 -> regions 4(m)x2(n) of 4x16; 512 blocks, 2/CU
    gemm_bt<1, 256, 128, 128, 64, 3><<<dim3(32, 16), 256, 0, stream>>>(
        hn, W1b, 1024, 1024, 1024, W1_b, 4096, 4096, 4, 4, 16, nullptr, nullptr, act);
    // h += 0.5*(act @ W2^T): split-K=4 (z), 256x128 tiles, 512 blocks, 2/CU
    // per z: M-tiles 16, N-tiles 8 -> regions 4(m)x2(n) of 4x4
    gemm_bt<2, 256, 128, 128, 64, 3><<<dim3(8, 16, 4), 256, 0, stream>>>(
        act, W2b, 1024, 4096, 4096, nullptr, 1024, 1024, 4, 4, 4, h, nullptr, nullptr);
  }

  cvt_h<<<4096, 256, 0, stream>>>(h, hb);
  // M-tiles 32, N-tiles 8 -> regions 4x2 of 8x4
  gemm_bt<3, 128, 128, 64, 64, 3><<<dim3(8, 32), 256, 0, stream>>>(
      hb, hwb, 1024, 1024, 1024, head_b, 1000, 1000, 8, 4, 4, (float*)d_out, nullptr, nullptr);
}

// Round 4
// 4684.228 us; speedup vs baseline: 1.2146x; 1.2146x over previous
//
#include <hip/hip_runtime.h>
#include <math.h>

#define GAMMA 0.5f

typedef __bf16 bf16x8 __attribute__((ext_vector_type(8)));
typedef float  f32x4  __attribute__((ext_vector_type(4)));

__device__ __forceinline__ unsigned short f2bf(float f){
  union { float ff; unsigned u; } x; x.ff = f;
  return (unsigned short)((x.u + 0x7fffu + ((x.u >> 16) & 1u)) >> 16);
}

__device__ __forceinline__ float fast_tanh(float v){
  float e = __expf(v + v);
  return 1.f - 2.f * __builtin_amdgcn_rcpf(e + 1.f);
}

__device__ __forceinline__ void gload16(const void* g, void* l){
  __builtin_amdgcn_global_load_lds((const __attribute__((address_space(1))) void*)g,
                                   (__attribute__((address_space(3))) void*)l,
                                   16, 0, 0);
}

template<int N> __device__ __forceinline__ void waitvm(){
  static_assert(N==0 || N==3 || N==4 || N==6, "add literal case");
  if      constexpr (N==0) asm volatile("s_waitcnt vmcnt(0)" ::: "memory");
  else if constexpr (N==3) asm volatile("s_waitcnt vmcnt(3)" ::: "memory");
  else if constexpr (N==4) asm volatile("s_waitcnt vmcnt(4)" ::: "memory");
  else if constexpr (N==6) asm volatile("s_waitcnt vmcnt(6)" ::: "memory");
}

// ============================================================================
// gemm8: 8-phase 256x256 GEMM, C = A[M,Ktot] * B[N,Ktot]^T. BK=64, 512 thr =
// 8 waves (2M x 4N), each wave owns 128x64 (acc[8][4] f32x4 = 128 VGPR).
// LDS: 2 K-tile double buffer per operand, 128 KiB total, 1 block/CU.
// Slot layout (conflict-free, proven 0-conflict in round 3): 16B chunk
// (row, kc) -> slot ((row>>4)*2 + (kc>>2))*64 + (kc&3)*16 + (row&15); a
// fragment read is 64 consecutive 16B chunks (lane-linear).
// Schedule per iteration (K-tiles t0=2it->buf0 ph1-4, t1=2it+1->buf1 ph5-8),
// stage 1 half-tile per phase; slot-free proof: B-halves of a buffer are
// last read in its K-tile's ph2, A-halves in ph3; each stage targets a half
// separated from its last read by >=1 barrier:
//   ph1: Ah0(b1,t1)  ph2: Ah1(b1,t1)  ph3: Bh0(b0,t0+2)  ph4: Bh1(b0,t0+2)
//   ph5: Ah0(b0,t0+2) ph6: Ah1(b0,t0+2) ph7: Bh0(b1,t1+2) ph8: Bh1(b1,t1+2)
// vmcnt(4) after stage at ph4 & ph8 (2 loads/half, allow 2 newest halves in
// flight): guarantees the next K-tile's 4 halves landed before its ds_reads.
// Never vmcnt(0) in the loop. Last iteration's overshoot stages read adjacent
// mapped ws buffers (harmless, never computed); drained by final vmcnt(0).
// MODE 1: U0[idx]=bf16(tanh(v+bias));  MODE 2: F0[blockIdx.z*pstride+idx]=v
// ============================================================================
template<int MODE>
__global__ __launch_bounds__(512, 1)
void gemm8(const unsigned short* __restrict__ A,
           const unsigned short* __restrict__ B,
           int K, int lda, int ldb, const float* __restrict__ bias,
           int ldc, int RM, int MR, int RN,
           float* __restrict__ F0, long pstride,
           unsigned short* __restrict__ U0)
{
  const int bid = blockIdx.y * gridDim.x + blockIdx.x;
  const int xcd = bid & 7, kk = bid >> 3;
  const int m0 = ((xcd % MR) * RM + (kk % RM)) * 256;
  const int n0 = ((xcd / MR) * RN + (kk / RM)) * 256;
  const long kz = (long)blockIdx.z * K;
  A += kz; B += kz;
  if (MODE == 2) F0 += (long)blockIdx.z * pstride;

  const int t = threadIdx.x, l = t & 63;
  const int w = t >> 6, wr = w >> 2, wc = w & 3;
  const int lr = l & 15, quad = l >> 4;

  __shared__ __align__(16) unsigned short lgA[2][256 * 64];
  __shared__ __align__(16) unsigned short lgB[2][256 * 64];

  f32x4 acc[8][4];
  #pragma unroll
  for (int i = 0; i < 8; i++)
    #pragma unroll
    for (int j = 0; j < 4; j++) acc[i][j] = (f32x4){0.f, 0.f, 0.f, 0.f};

  bf16x8 af[4][2];      // A fragments for current qm (4 mi x 2 ks)
  bf16x8 bg[2][2][2];   // B fragments for both qn (qn x nj2 x ks)

#define STGH(GP, g0, ld, LP, kt, hh) { \
  _Pragma("unroll") \
  for (int j = 0; j < 2; j++) { \
    const int c = (hh) * 1024 + j * 512 + t; \
    const int row = ((c >> 7) << 4) | (c & 15); \
    const int kc = ((c >> 6) & 1) * 4 + ((c >> 4) & 3); \
    gload16((GP) + (long)((g0) + row) * (ld) + (kt) + kc * 8, (char*)(LP) + c * 16); \
  } }

#define RDA(buf, qm) { \
  _Pragma("unroll") \
  for (int mi2 = 0; mi2 < 4; mi2++) \
    _Pragma("unroll") \
    for (int ks = 0; ks < 2; ks++) \
      af[mi2][ks] = *(const bf16x8*)&lgA[buf][((((wr * 8 + (qm) * 4 + mi2) << 1) | ks) * 64 + l) * 8]; }

#define RDB(buf, qn) { \
  _Pragma("unroll") \
  for (int nj2 = 0; nj2 < 2; nj2++) \
    _Pragma("unroll") \
    for (int ks = 0; ks < 2; ks++) \
      bg[qn][nj2][ks] = *(const bf16x8*)&lgB[buf][((((wc * 4 + (qn) * 2 + nj2) << 1) | ks) * 64 + l) * 8]; }

#define MFMAQ(qm, qn) { \
  __builtin_amdgcn_s_setprio(1); \
  _Pragma("unroll") \
  for (int mi2 = 0; mi2 < 4; mi2++) \
    _Pragma("unroll") \
    for (int nj2 = 0; nj2 < 2; nj2++) \
      _Pragma("unroll") \
      for (int ks = 0; ks < 2; ks++) \
        acc[(qm) * 4 + mi2][(qn) * 2 + nj2] = __builtin_amdgcn_mfma_f32_16x16x32_bf16( \
            af[mi2][ks], bg[qn][nj2][ks], acc[(qm) * 4 + mi2][(qn) * 2 + nj2], 0, 0, 0); \
  __builtin_amdgcn_s_setprio(0); }

#define BAR __builtin_amdgcn_s_barrier()

  // Prologue: tile0 (buf0) complete + tile1 (buf1) B-halves (A of tile1
  // arrives at ph1/ph2 of iteration 0).
  STGH(A, m0, lda, lgA[0], 0, 0)
  STGH(A, m0, lda, lgA[0], 0, 1)
  STGH(B, n0, ldb, lgB[0], 0, 0)
  STGH(B, n0, ldb, lgB[0], 0, 1)
  STGH(B, n0, ldb, lgB[1], 64, 0)
  STGH(B, n0, ldb, lgB[1], 64, 1)
  waitvm<4>();            // tile0's 8 loads retired; tile1 B may fly
  BAR;

  const int NH = K >> 7;  // iterations; 2 K-tiles of 64 each
  for (int it = 0; it < NH; ++it) {
    const int kA = it * 128;
    // ph1: t0 quad(0,0); stage Ah0(b1,t1)
    RDA(0, 0) RDB(0, 0)
    STGH(A, m0, lda, lgA[1], kA + 64, 0)
    BAR; MFMAQ(0, 0) BAR;
    // ph2: t0 quad(0,1); stage Ah1(b1,t1)
    RDB(0, 1)
    STGH(A, m0, lda, lgA[1], kA + 64, 1)
    BAR; MFMAQ(0, 1) BAR;
    // ph3: t0 quad(1,0); stage Bh0(b0,t0+2)
    RDA(0, 1)
    STGH(B, n0, ldb, lgB[0], kA + 128, 0)
    BAR; MFMAQ(1, 0) BAR;
    // ph4: t0 quad(1,1); stage Bh1(b0,t0+2); gate t1 readiness
    STGH(B, n0, ldb, lgB[0], kA + 128, 1)
    waitvm<4>();
    BAR; MFMAQ(1, 1) BAR;
    // ph5: t1 quad(0,0); stage Ah0(b0,t0+2)
    RDA(1, 0) RDB(1, 0)
    STGH(A, m0, lda, lgA[0], kA + 128, 0)
    BAR; MFMAQ(0, 0) BAR;
    // ph6: t1 quad(0,1); stage Ah1(b0,t0+2)
    RDB(1, 1)
    STGH(A, m0, lda, lgA[0], kA + 128, 1)
    BAR; MFMAQ(0, 1) BAR;
    // ph7: t1 quad(1,0); stage Bh0(b1,t1+2)
    RDA(1, 1)
    STGH(B, n0, ldb, lgB[1], kA + 192, 0)
    BAR; MFMAQ(1, 0) BAR;
    // ph8: t1 quad(1,1); stage Bh1(b1,t1+2); gate t0+2 readiness
    STGH(B, n0, ldb, lgB[1], kA + 192, 1)
    waitvm<4>();
    BAR; MFMAQ(1, 1) BAR;
  }
  waitvm<0>();            // drain overshoot stages before epilogue/endpgm

#undef STGH
#undef RDA
#undef RDB
#undef MFMAQ
#undef BAR

  #pragma unroll
  for (int mi = 0; mi < 8; mi++) {
    const int mb = m0 + wr * 128 + mi * 16 + quad * 4;
    #pragma unroll
    for (int nj = 0; nj < 4; nj++) {
      const int n = n0 + wc * 64 + nj * 16 + lr;
      const float bia = (MODE == 1) ? bias[n] : 0.f;
      #pragma unroll
      for (int r = 0; r < 4; r++) {
        const long idx = (long)(mb + r) * ldc + n;
        const float v = acc[mi][nj][r] + bia;
        if (MODE == 1) U0[idx] = f2bf(fast_tanh(v));
        else           F0[idx] = v;
      }
    }
  }
}

// ============================================================================
// gemm_bt: 2-phase 4-wave kernel (conflict-free LDS layout, counted-vmcnt
// ring). Used for G0/G3 (odd shapes) and fallback G2.
// MODE 0: F0=v; F1=v   MODE 2: F0 = .5*F0 + .5*(v + R0)   MODE 3: masked store
// ============================================================================
template<int MODE, int BM, int BN, int WM, int WN, int D>
__global__ __launch_bounds__(256, 2)
void gemm_bt(const unsigned short* __restrict__ A,
             const unsigned short* __restrict__ B,
             int K, int lda, int ldb, const float* __restrict__ bias,
             int ldc, int nmax, int RM, int MR, int RN,
             float* __restrict__ F0, float* __restrict__ F1,
             unsigned short* __restrict__ U0,
             const float* __restrict__ R0)
{
  static_assert(BM / WM == 2 && BN / WN == 2, "4 waves arranged 2x2");
  constexpr int MI = WM / 16;
  constexpr int JN = WN / 16;
  constexpr int L  = BM / 64 + BN / 64;
  const int bid = blockIdx.y * gridDim.x + blockIdx.x;
  const int xcd = bid & 7, kk = bid >> 3;
  const int m0 = ((xcd % MR) * RM + (kk % RM)) * BM;
  const int n0 = ((xcd / MR) * RN + (kk / RM)) * BN;

  const int t = threadIdx.x, w = t >> 6, l = t & 63;
  __shared__ __align__(16) unsigned short lgA[D][BM * 32];
  __shared__ __align__(16) unsigned short lgB[D][BN * 32];
  f32x4 acc[MI][JN];
  #pragma unroll
  for (int i = 0; i < MI; i++)
    #pragma unroll
    for (int j = 0; j < JN; j++) acc[i][j] = (f32x4){0.f, 0.f, 0.f, 0.f};

  const int wm = (w & 1) * WM, wn = (w >> 1) * WN;
  const int lr = l & 15, quad = l >> 4;

#define STAGE(kt, buf) { \
    _Pragma("unroll") \
    for (int j = 0; j < BM / 64; j++) { \
      const int c = j * 256 + t; \
      const int row = ((c >> 6) << 4) | (c & 15), kq = (c >> 4) & 3; \
      gload16(A + (long)(m0 + row) * lda + (kt) + kq * 8, (char*)lgA[(buf)] + c * 16); \
    } \
    _Pragma("unroll") \
    for (int j = 0; j < BN / 64; j++) { \
      const int c = j * 256 + t; \
      const int row = ((c >> 6) << 4) | (c & 15), kq = (c >> 4) & 3; \
      gload16(B + (long)(n0 + row) * ldb + (kt) + kq * 8, (char*)lgB[(buf)] + c * 16); \
    } }

#define COMPUTE(buf) { \
    bf16x8 af[MI], bg[JN]; \
    _Pragma("unroll") \
    for (int i = 0; i < MI; i++) \
      af[i] = *(const bf16x8*)&lgA[(buf)][((((wm >> 4) + i) << 6) + l) * 8]; \
    _Pragma("unroll") \
    for (int j = 0; j < JN; j++) \
      bg[j] = *(const bf16x8*)&lgB[(buf)][((((wn >> 4) + j) << 6) + l) * 8]; \
    _Pragma("unroll") \
    for (int i = 0; i < MI; i++) \
      _Pragma("unroll") \
      for (int j = 0; j < JN; j++) \
        acc[i][j] = __builtin_amdgcn_mfma_f32_16x16x32_bf16(af[i], bg[j], acc[i][j], 0, 0, 0); \
  }

  const int NT = K >> 5;
  #pragma unroll
  for (int i = 0; i < D - 1; ++i) STAGE(i * 32, i)

  int cur = 0;
  for (int tt = 0; tt < NT - (D - 1); ++tt) {
    waitvm<L * (D - 2)>();
    __builtin_amdgcn_s_barrier();
    const int prv = (cur == 0) ? D - 1 : cur - 1;
    STAGE((tt + D - 1) * 32, prv)
    COMPUTE(cur)
    cur = (cur == D - 1) ? 0 : cur + 1;
  }
  if constexpr (D == 4) {
    waitvm<2 * L>();
    __builtin_amdgcn_s_barrier();
    COMPUTE(cur)
    cur = (cur == D - 1) ? 0 : cur + 1;
  }
  waitvm<L>();
  __builtin_amdgcn_s_barrier();
  COMPUTE(cur)
  cur = (cur == D - 1) ? 0 : cur + 1;
  waitvm<0>();
  __builtin_amdgcn_s_barrier();
  COMPUTE(cur)
#undef STAGE
#undef COMPUTE

  #pragma unroll
  for (int i = 0; i < MI; i++) {
    const int mb = m0 + wm + i * 16 + quad * 4;
    #pragma unroll
    for (int j = 0; j < JN; j++) {
      const int n = n0 + wn + j * 16 + lr;
      float bia = 0.f;
      if (MODE == 3) { if (n < nmax) bia = bias[n]; } else { bia = bias[n]; }
      #pragma unroll
      for (int r = 0; r < 4; r++) {
        const long m = mb + r;
        const float v = acc[i][j][r] + bia;
        const long idx = m * (long)ldc + n;
        if (MODE == 0)      { F0[idx] = v; F1[idx] = v; }
        else if (MODE == 2) { F0[idx] = (1.f - GAMMA) * F0[idx] + GAMMA * (v + R0[idx]); }
        else                { if (n < nmax) F0[idx] = v; }
      }
    }
  }
}

// LayerNorm over rows of 1024 fp32 -> bf16. COMB=1 first folds the split-K
// combine: h <- .5h + .5*(sum_z P[z] + b2 + xemb), writes h back, then LNs
// the NEW h. Stats computed on per-thread v (post-combine) -- matches ref.
template<int COMB>
__global__ __launch_bounds__(256)
void ln_bf16(float* __restrict__ h, const float* __restrict__ gw,
             const float* __restrict__ gb, unsigned short* __restrict__ o,
             const float* __restrict__ xemb, const float* __restrict__ b2,
             const float* __restrict__ P, long ps)
{
  const int row = blockIdx.x, t = threadIdx.x;
  const long base = (long)row * 1024;
  float4 v = ((const float4*)(h + base))[t];
  if (COMB) {
    const float4 p0 = ((const float4*)(P + base))[t];
    const float4 p1 = ((const float4*)(P + ps + base))[t];
    const float4 p2 = ((const float4*)(P + 2 * ps + base))[t];
    const float4 p3 = ((const float4*)(P + 3 * ps + base))[t];
    const float4 xe = ((const float4*)(xemb + base))[t];
    const float4 bb = ((const float4*)b2)[t];
    v.x = (1.f - GAMMA) * v.x + GAMMA * (p0.x + p1.x + p2.x + p3.x + xe.x + bb.x);
    v.y = (1.f - GAMMA) * v.y + GAMMA * (p0.y + p1.y + p2.y + p3.y + xe.y + bb.y);
    v.z = (1.f - GAMMA) * v.z + GAMMA * (p0.z + p1.z + p2.z + p3.z + xe.z + bb.z);
    v.w = (1.f - GAMMA) * v.w + GAMMA * (p0.w + p1.w + p2.w + p3.w + xe.w + bb.w);
    ((float4*)(h + base))[t] = v;
  }
  float s = v.x + v.y + v.z + v.w;
  float q = v.x * v.x + v.y * v.y + v.z * v.z + v.w * v.w;
  #pragma unroll
  for (int o2 = 32; o2 > 0; o2 >>= 1) { s += __shfl_xor(s, o2); q += __shfl_xor(q, o2); }
  __shared__ float rs[4], rq[4];
  if ((t & 63) == 0) { rs[t >> 6] = s; rq[t >> 6] = q; }
  __syncthreads();
  s = rs[0] + rs[1] + rs[2] + rs[3];
  q = rq[0] + rq[1] + rq[2] + rq[3];
  const float mu  = s * (1.f / 1024.f);
  const float inv = rsqrtf(q * (1.f / 1024.f) - mu * mu + 1e-5f);
  const float4 wv = ((const float4*)gw)[t];
  const float4 bv = ((const float4*)gb)[t];
  ushort4 u;
  u.x = f2bf((v.x - mu) * inv * wv.x + bv.x);
  u.y = f2bf((v.y - mu) * inv * wv.y + bv.y);
  u.z = f2bf((v.z - mu) * inv * wv.z + bv.z);
  u.w = f2bf((v.w - mu) * inv * wv.w + bv.w);
  ((ushort4*)(o + base))[t] = u;
}

// f32 -> bf16 with zero padding
__global__ __launch_bounds__(256)
void cvt_pad(const float* __restrict__ src, unsigned short* __restrict__ dst,
             int src_rows, int src_cols, int dst_cols)
{
  const int r = blockIdx.y;
  const int c = blockIdx.x * 256 + threadIdx.x;
  if (c >= dst_cols) return;
  unsigned short v = 0;
  if (r < src_rows && c < src_cols) v = f2bf(src[(long)r * src_cols + c]);
  dst[(long)r * dst_cols + c] = v;
}

// h fp32 -> bf16; COMB=1 applies the final split-K combine first.
template<int COMB>
__global__ __launch_bounds__(256)
void cvt_h(const float* __restrict__ h, unsigned short* __restrict__ o,
           const float* __restrict__ xemb, const float* __restrict__ b2,
           const float* __restrict__ P, long ps)
{
  const long i = (long)blockIdx.x * 256 + threadIdx.x;
  float4 v = ((const float4*)h)[i];
  if (COMB) {
    const float4 p0 = ((const float4*)P)[i];
    const float4 p1 = ((const float4*)(P + ps))[i];
    const float4 p2 = ((const float4*)(P + 2 * ps))[i];
    const float4 p3 = ((const float4*)(P + 3 * ps))[i];
    const float4 xe = ((const float4*)xemb)[i];
    const float4 bb = ((const float4*)b2)[(int)(i & 255)];
    v.x = (1.f - GAMMA) * v.x + GAMMA * (p0.x + p1.x + p2.x + p3.x + xe.x + bb.x);
    v.y = (1.f - GAMMA) * v.y + GAMMA * (p0.y + p1.y + p2.y + p3.y + xe.y + bb.y);
    v.z = (1.f - GAMMA) * v.z + GAMMA * (p0.z + p1.z + p2.z + p3.z + xe.z + bb.z);
    v.w = (1.f - GAMMA) * v.w + GAMMA * (p0.w + p1.w + p2.w + p3.w + xe.w + bb.w);
  }
  ushort4 u;
  u.x = f2bf(v.x); u.y = f2bf(v.y); u.z = f2bf(v.z); u.w = f2bf(v.w);
  ((ushort4*)o)[i] = u;
}

extern "C" void kernel_launch(void* const* d_in, const int* in_sizes, int n_in,
                              void* d_out, int out_size, void* d_ws, size_t ws_size,
                              hipStream_t stream)
{
  const float* x       = (const float*)d_in[0];
  const float* embed_w = (const float*)d_in[1];
  const float* embed_b = (const float*)d_in[2];
  const float* W1_w    = (const float*)d_in[3];
  const float* W1_b    = (const float*)d_in[4];
  const float* W2_w    = (const float*)d_in[5];
  const float* W2_b    = (const float*)d_in[6];
  const float* norm_w  = (const float*)d_in[7];
  const float* norm_b  = (const float*)d_in[8];
  const float* head_w  = (const float*)d_in[9];
  const float* head_b  = (const float*)d_in[10];
  (void)in_sizes; (void)n_in; (void)out_size;

  char* ws = (char*)d_ws;
  unsigned short* W1b  = (unsigned short*)(ws);              //  8,388,608  W1 bf16   [4096][1024]
  unsigned short* W2b  = (unsigned short*)(ws + 8388608);    //  8,388,608  W2 bf16   [1024][4096]
  unsigned short* xb   = (unsigned short*)(ws + 16777216);   //  6,553,600  x bf16    [4096][800]
  unsigned short* ewb  = (unsigned short*)(ws + 23330816);   //  1,638,400  embW bf16 [1024][800]
  unsigned short* hwb  = (unsigned short*)(ws + 24969216);   //  2,097,152  headW bf16[1024][1024]
  float*          xemb = (float*)(ws + 27066368);            // 16,777,216  x_emb f32 [4096][1024]
  float*          h    = (float*)(ws + 43843584);            // 16,777,216  h f32     [4096][1024]
  unsigned short* hn   = (unsigned short*)(ws + 60620800);   //  8,388,608  ln(h) bf16[4096][1024]
  unsigned short* act  = (unsigned short*)(ws + 69009408);   // 33,554,432  ffn act   [4096][4096]
  unsigned short* hb   = (unsigned short*)(ws + 102563840);  //  8,388,608  h bf16    [4096][1024]
  float*          P    = (float*)(ws + 110952448);           // 67,108,864  partials  [4][4096][1024]
  const bool splitk = ws_size >= (size_t)178061312;
  const long PS = 4194304;  // partial stride in floats

  cvt_pad<<<dim3(4, 4096), 256, 0, stream>>>(W1_w, W1b, 4096, 1024, 1024);
  cvt_pad<<<dim3(16, 1024), 256, 0, stream>>>(W2_w, W2b, 1024, 4096, 4096);
  cvt_pad<<<dim3(4, 4096), 256, 0, stream>>>(x, xb, 4096, 784, 800);
  cvt_pad<<<dim3(4, 1024), 256, 0, stream>>>(embed_w, ewb, 1024, 784, 800);
  cvt_pad<<<dim3(4, 1024), 256, 0, stream>>>(head_w, hwb, 1000, 1024, 1024);

  // x_emb = x @ embed_w^T + embed_b ; h = x_emb
  gemm_bt<0, 128, 128, 64, 64, 3><<<dim3(8, 32), 256, 0, stream>>>(
      xb, ewb, 800, 800, 800, embed_b, 1024, 1024, 8, 4, 4, xemb, h, nullptr, nullptr);

  for (int s = 0; s < 30; s++) {
    if (splitk && s > 0)
      ln_bf16<1><<<4096, 256, 0, stream>>>(h, norm_w, norm_b, hn, xemb, W2_b, P, PS);
    else
      ln_bf16<0><<<4096, 256, 0, stream>>>(h, norm_w, norm_b, hn, nullptr, nullptr, nullptr, 0);

    // act = tanh(hn @ W1^T + b1): 8-phase 256^2, 16x16 tiles = 256 blocks (1/CU)
    gemm8<1><<<dim3(16, 16), 512, 0, stream>>>(
        hn, W1b, 1024, 1024, 1024, W1_b, 4096, 4, 4, 8, nullptr, 0, act);

    if (splitk) {
      // P[z] = act[:, z*1024:+1024] @ W2^T chunk: 8-phase, 16x4x4z = 256 blocks
      gemm8<2><<<dim3(4, 16, 4), 512, 0, stream>>>(
          act, W2b, 1024, 4096, 4096, nullptr, 1024, 2, 8, 4, P, PS, nullptr);
    } else {
      // h = .5h + .5(act @ W2^T + b2 + xemb): 2-phase fallback, 2 blocks/CU
      gemm_bt<2, 128, 64, 64, 32, 4><<<dim3(16, 32), 256, 0, stream>>>(
          act, W2b, 4096, 4096, 4096, W2_b, 1024, 1024, 8, 4, 8, h, nullptr, nullptr, xemb);
    }
  }

  if (splitk)
    cvt_h<1><<<4096, 256, 0, stream>>>(h, hb, xemb, W2_b, P, PS);
  else
    cvt_h<0><<<4096, 256, 0, stream>>>(h, hb, nullptr, nullptr, nullptr, 0);

  gemm_bt<3, 128, 128, 64, 64, 3><<<dim3(8, 32), 256, 0, stream>>>(
      hb, hwb, 1024, 1024, 1024, head_b, 1000, 1000, 8, 4, 4, (float*)d_out, nullptr, nullptr, nullptr);
}

// Round 6
// 4383.949 us; speedup vs baseline: 1.2977x; 1.0685x over previous
//
#include <hip/hip_runtime.h>
#include <math.h>

#define GAMMA 0.5f

typedef __bf16 bf16x8 __attribute__((ext_vector_type(8)));
typedef float  f32x4  __attribute__((ext_vector_type(4)));

__device__ __forceinline__ unsigned short f2bf(float f){
  union { float ff; unsigned u; } x; x.ff = f;
  return (unsigned short)((x.u + 0x7fffu + ((x.u >> 16) & 1u)) >> 16);
}

__device__ __forceinline__ float bf2f(unsigned short u){
  union { unsigned u; float f; } x; x.u = (unsigned)u << 16;
  return x.f;
}

__device__ __forceinline__ float fast_tanh(float v){
  float e = __expf(v + v);
  return 1.f - 2.f * __builtin_amdgcn_rcpf(e + 1.f);
}

__device__ __forceinline__ void gload16(const void* g, void* l){
  __builtin_amdgcn_global_load_lds((const __attribute__((address_space(1))) void*)g,
                                   (__attribute__((address_space(3))) void*)l,
                                   16, 0, 0);
}

template<int N> __device__ __forceinline__ void waitvm(){
  static_assert(N==0 || N==2 || N==3 || N==4 || N==6 || N==8 || N==12,
                "add literal case");
  if      constexpr (N==0)  asm volatile("s_waitcnt vmcnt(0)"  ::: "memory");
  else if constexpr (N==2)  asm volatile("s_waitcnt vmcnt(2)"  ::: "memory");
  else if constexpr (N==3)  asm volatile("s_waitcnt vmcnt(3)"  ::: "memory");
  else if constexpr (N==4)  asm volatile("s_waitcnt vmcnt(4)"  ::: "memory");
  else if constexpr (N==6)  asm volatile("s_waitcnt vmcnt(6)"  ::: "memory");
  else if constexpr (N==8)  asm volatile("s_waitcnt vmcnt(8)"  ::: "memory");
  else if constexpr (N==12) asm volatile("s_waitcnt vmcnt(12)" ::: "memory");
}

// ============================================================================
// gemm_bt: 2-phase 4-wave GEMM, C = A[M,Ktot]*B[N,Ktot]^T (row strides
// lda/ldb). blockIdx.z selects a K-chunk of length K (split-K; z=0-only grids
// unaffected). Tile BM x BN, BK=32, 256 threads = 4 waves 2x2, wave owns
// WM x WN, acc [WM/16][WN/16] f32x4.
// LDS slot layout (PROVEN 0-conflict, round 3): 16B chunk (row,kq) -> slot
// (row>>4)*64 + kq*16 + (row&15); fragment reads are 64 consecutive 16B
// chunks (lane-linear). global_load_lds dest lane-linear; permutation applied
// to the GLOBAL source address.
// K-loop: D-ring + counted vmcnt (never 0 in steady state), 1 barrier/K-step.
// Epilogues:
//  MODE 0: F0=v; F1=v (f32 direct)        MODE 3: masked f32 direct (head)
//  MODE 2: F0 = .5*F0 + .5*(v+R0) (f32 RMW direct; fallback path)
//  MODE 1: U0 = bf16(tanh(v+bias))  -- LDS-PACKED: full 256B row segments
//  MODE 4: U0 = bf16(v), U0 += z*pstride (pstride in 'nmax') -- LDS-PACKED
// Packed epilogue kills the measured 1.7-1.9x write amplification of 32B
// lane-segment stores (r4 counters: act 33.5->62 MB, P 64->107 MB).
// ============================================================================
template<int MODE, int BM, int BN, int WM, int WN, int D>
__global__ __launch_bounds__(256, 2)
void gemm_bt(const unsigned short* __restrict__ A,
             const unsigned short* __restrict__ B,
             int K, int lda, int ldb, const float* __restrict__ bias,
             int ldc, int nmax, int RM, int MR, int RN,
             float* __restrict__ F0, float* __restrict__ F1,
             unsigned short* __restrict__ U0,
             const float* __restrict__ R0)
{
  static_assert(BM / WM == 2 && BN / WN == 2, "4 waves arranged 2x2");
  constexpr int MI = WM / 16;
  constexpr int JN = WN / 16;
  constexpr int L  = BM / 64 + BN / 64;
  const int bid = blockIdx.y * gridDim.x + blockIdx.x;
  const int xcd = bid & 7, kk = bid >> 3;
  const int m0 = ((xcd % MR) * RM + (kk % RM)) * BM;
  const int n0 = ((xcd / MR) * RN + (kk / RM)) * BN;
  const long kz = (long)blockIdx.z * K;
  A += kz; B += kz;
  if (MODE == 4) U0 += (long)blockIdx.z * (long)nmax;

  const int t = threadIdx.x, w = t >> 6, l = t & 63;

  constexpr int STG = D * (BM + BN) * 32;                     // staging u16
  constexpr int PCK = (MODE == 1 || MODE == 4) ? BM * BN : 0; // pack u16
  constexpr int SH  = STG > PCK ? STG : PCK;
  __shared__ __align__(16) unsigned short sh[SH];
  unsigned short* lgA = sh;                 // [D][BM*32]
  unsigned short* lgB = sh + D * BM * 32;   // [D][BN*32]

  f32x4 acc[MI][JN];
  #pragma unroll
  for (int i = 0; i < MI; i++)
    #pragma unroll
    for (int j = 0; j < JN; j++) acc[i][j] = (f32x4){0.f, 0.f, 0.f, 0.f};

  const int wm = (w & 1) * WM, wn = (w >> 1) * WN;
  const int lr = l & 15, quad = l >> 4;

#define STAGE(kt, buf) { \
    _Pragma("unroll") \
    for (int j = 0; j < BM / 64; j++) { \
      const int c = j * 256 + t; \
      const int row = ((c >> 6) << 4) | (c & 15), kq = (c >> 4) & 3; \
      gload16(A + (long)(m0 + row) * lda + (kt) + kq * 8, (char*)(lgA + (buf) * BM * 32) + c * 16); \
    } \
    _Pragma("unroll") \
    for (int j = 0; j < BN / 64; j++) { \
      const int c = j * 256 + t; \
      const int row = ((c >> 6) << 4) | (c & 15), kq = (c >> 4) & 3; \
      gload16(B + (long)(n0 + row) * ldb + (kt) + kq * 8, (char*)(lgB + (buf) * BN * 32) + c * 16); \
    } }

#define COMPUTE(buf) { \
    bf16x8 af[MI], bg[JN]; \
    _Pragma("unroll") \
    for (int i = 0; i < MI; i++) \
      af[i] = *(const bf16x8*)&lgA[(buf) * BM * 32 + ((((wm >> 4) + i) << 6) + l) * 8]; \
    _Pragma("unroll") \
    for (int j = 0; j < JN; j++) \
      bg[j] = *(const bf16x8*)&lgB[(buf) * BN * 32 + ((((wn >> 4) + j) << 6) + l) * 8]; \
    _Pragma("unroll") \
    for (int i = 0; i < MI; i++) \
      _Pragma("unroll") \
      for (int j = 0; j < JN; j++) \
        acc[i][j] = __builtin_amdgcn_mfma_f32_16x16x32_bf16(af[i], bg[j], acc[i][j], 0, 0, 0); \
  }

  const int NT = K >> 5;
  #pragma unroll
  for (int i = 0; i < D - 1; ++i) STAGE(i * 32, i)

  int cur = 0;
  for (int tt = 0; tt < NT - (D - 1); ++tt) {
    waitvm<L * (D - 2)>();
    __builtin_amdgcn_s_barrier();
    const int prv = (cur == 0) ? D - 1 : cur - 1;
    STAGE((tt + D - 1) * 32, prv)
    COMPUTE(cur)
    cur = (cur == D - 1) ? 0 : cur + 1;
  }
  if constexpr (D == 4) {
    waitvm<2 * L>();
    __builtin_amdgcn_s_barrier();
    COMPUTE(cur)
    cur = (cur == D - 1) ? 0 : cur + 1;
  }
  waitvm<L>();
  __builtin_amdgcn_s_barrier();
  COMPUTE(cur)
  cur = (cur == D - 1) ? 0 : cur + 1;
  waitvm<0>();
  __builtin_amdgcn_s_barrier();
  COMPUTE(cur)
#undef STAGE
#undef COMPUTE

  if constexpr (MODE == 1 || MODE == 4) {
    // ---- LDS-packed bf16 epilogue: assemble [BM][BN] tile, write full rows.
    __syncthreads();                       // ring reads done; reuse sh
    #pragma unroll
    for (int i = 0; i < MI; i++) {
      const int rb = wm + i * 16 + quad * 4;
      #pragma unroll
      for (int j = 0; j < JN; j++) {
        const int cl = wn + j * 16 + lr;
        const float bia = (MODE == 1) ? bias[n0 + cl] : 0.f;
        #pragma unroll
        for (int r = 0; r < 4; r++) {
          const float v = acc[i][j][r] + bia;
          sh[(rb + r) * BN + cl] = (MODE == 1) ? f2bf(fast_tanh(v)) : f2bf(v);
        }
      }
    }
    __syncthreads();
    constexpr int CPR = BN / 8;            // 16B chunks per row
    constexpr int RPP = 256 / CPR;         // rows per pass
    const int ch = t & (CPR - 1), rw = t / CPR;
    #pragma unroll
    for (int p = 0; p < BM / RPP; p++) {
      const int row = p * RPP + rw;
      *(bf16x8*)&U0[(long)(m0 + row) * ldc + n0 + ch * 8] =
          *(const bf16x8*)&sh[row * BN + ch * 8];
    }
  } else {
    #pragma unroll
    for (int i = 0; i < MI; i++) {
      const int mb = m0 + wm + i * 16 + quad * 4;
      #pragma unroll
      for (int j = 0; j < JN; j++) {
        const int n = n0 + wn + j * 16 + lr;
        float bia = 0.f;
        if (MODE == 3) { if (n < nmax) bia = bias[n]; } else { bia = bias[n]; }
        #pragma unroll
        for (int r = 0; r < 4; r++) {
          const long m = mb + r;
          const float v = acc[i][j][r] + bia;
          const long idx = m * (long)ldc + n;
          if (MODE == 0)      { F0[idx] = v; F1[idx] = v; }
          else if (MODE == 2) { F0[idx] = (1.f - GAMMA) * F0[idx] + GAMMA * (v + R0[idx]); }
          else                { if (n < nmax) F0[idx] = v; }
        }
      }
    }
  }
}

// LayerNorm over rows of 1024 fp32 -> bf16. COMB=1 first folds the split-K
// combine: h <- .5h + .5*(sum_z P[z] + b2 + xemb)  (P is bf16), writes h,
// then LNs the NEW h (matches reference step ordering; validated r3/r4).
template<int COMB>
__global__ __launch_bounds__(256)
void ln_bf16(float* __restrict__ h, const float* __restrict__ gw,
             const float* __restrict__ gb, unsigned short* __restrict__ o,
             const float* __restrict__ xemb, const float* __restrict__ b2,
             const unsigned short* __restrict__ P, long ps)
{
  const int row = blockIdx.x, t = threadIdx.x;
  const long base = (long)row * 1024;
  float4 v = ((const float4*)(h + base))[t];
  if (COMB) {
    const ushort4 q0 = *(const ushort4*)&P[base + 4 * t];
    const ushort4 q1 = *(const ushort4*)&P[ps + base + 4 * t];
    const ushort4 q2 = *(const ushort4*)&P[2 * ps + base + 4 * t];
    const ushort4 q3 = *(const ushort4*)&P[3 * ps + base + 4 * t];
    const float4 xe = ((const float4*)(xemb + base))[t];
    const float4 bb = ((const float4*)b2)[t];
    v.x = (1.f - GAMMA) * v.x + GAMMA * (bf2f(q0.x) + bf2f(q1.x) + bf2f(q2.x) + bf2f(q3.x) + xe.x + bb.x);
    v.y = (1.f - GAMMA) * v.y + GAMMA * (bf2f(q0.y) + bf2f(q1.y) + bf2f(q2.y) + bf2f(q3.y) + xe.y + bb.y);
    v.z = (1.f - GAMMA) * v.z + GAMMA * (bf2f(q0.z) + bf2f(q1.z) + bf2f(q2.z) + bf2f(q3.z) + xe.z + bb.z);
    v.w = (1.f - GAMMA) * v.w + GAMMA * (bf2f(q0.w) + bf2f(q1.w) + bf2f(q2.w) + bf2f(q3.w) + xe.w + bb.w);
    ((float4*)(h + base))[t] = v;
  }
  float s = v.x + v.y + v.z + v.w;
  float q = v.x * v.x + v.y * v.y + v.z * v.z + v.w * v.w;
  #pragma unroll
  for (int o2 = 32; o2 > 0; o2 >>= 1) { s += __shfl_xor(s, o2); q += __shfl_xor(q, o2); }
  __shared__ float rs[4], rq[4];
  if ((t & 63) == 0) { rs[t >> 6] = s; rq[t >> 6] = q; }
  __syncthreads();
  s = rs[0] + rs[1] + rs[2] + rs[3];
  q = rq[0] + rq[1] + rq[2] + rq[3];
  const float mu  = s * (1.f / 1024.f);
  const float inv = rsqrtf(q * (1.f / 1024.f) - mu * mu + 1e-5f);
  const float4 wv = ((const float4*)gw)[t];
  const float4 bv = ((const float4*)gb)[t];
  ushort4 u;
  u.x = f2bf((v.x - mu) * inv * wv.x + bv.x);
  u.y = f2bf((v.y - mu) * inv * wv.y + bv.y);
  u.z = f2bf((v.z - mu) * inv * wv.z + bv.z);
  u.w = f2bf((v.w - mu) * inv * wv.w + bv.w);
  ((ushort4*)(o + base))[t] = u;
}

// f32 -> bf16 with zero padding
__global__ __launch_bounds__(256)
void cvt_pad(const float* __restrict__ src, unsigned short* __restrict__ dst,
             int src_rows, int src_cols, int dst_cols)
{
  const int r = blockIdx.y;
  const int c = blockIdx.x * 256 + threadIdx.x;
  if (c >= dst_cols) return;
  unsigned short v = 0;
  if (r < src_rows && c < src_cols) v = f2bf(src[(long)r * src_cols + c]);
  dst[(long)r * dst_cols + c] = v;
}

// h fp32 -> bf16; COMB=1 applies the final split-K combine first (P bf16).
template<int COMB>
__global__ __launch_bounds__(256)
void cvt_h(const float* __restrict__ h, unsigned short* __restrict__ o,
           const float* __restrict__ xemb, const float* __restrict__ b2,
           const unsigned short* __restrict__ P, long ps)
{
  const long i = (long)blockIdx.x * 256 + threadIdx.x;
  float4 v = ((const float4*)h)[i];
  if (COMB) {
    const ushort4 q0 = *(const ushort4*)&P[4 * i];
    const ushort4 q1 = *(const ushort4*)&P[ps + 4 * i];
    const ushort4 q2 = *(const ushort4*)&P[2 * ps + 4 * i];
    const ushort4 q3 = *(const ushort4*)&P[3 * ps + 4 * i];
    const float4 xe = ((const float4*)xemb)[i];
    const float4 bb = ((const float4*)b2)[(int)(i & 255)];
    v.x = (1.f - GAMMA) * v.x + GAMMA * (bf2f(q0.x) + bf2f(q1.x) + bf2f(q2.x) + bf2f(q3.x) + xe.x + bb.x);
    v.y = (1.f - GAMMA) * v.y + GAMMA * (bf2f(q0.y) + bf2f(q1.y) + bf2f(q2.y) + bf2f(q3.y) + xe.y + bb.y);
    v.z = (1.f - GAMMA) * v.z + GAMMA * (bf2f(q0.z) + bf2f(q1.z) + bf2f(q2.z) + bf2f(q3.z) + xe.z + bb.z);
    v.w = (1.f - GAMMA) * v.w + GAMMA * (bf2f(q0.w) + bf2f(q1.w) + bf2f(q2.w) + bf2f(q3.w) + xe.w + bb.w);
  }
  ushort4 u;
  u.x = f2bf(v.x); u.y = f2bf(v.y); u.z = f2bf(v.z); u.w = f2bf(v.w);
  ((ushort4*)o)[i] = u;
}

extern "C" void kernel_launch(void* const* d_in, const int* in_sizes, int n_in,
                              void* d_out, int out_size, void* d_ws, size_t ws_size,
                              hipStream_t stream)
{
  const float* x       = (const float*)d_in[0];
  const float* embed_w = (const float*)d_in[1];
  const float* embed_b = (const float*)d_in[2];
  const float* W1_w    = (const float*)d_in[3];
  const float* W1_b    = (const float*)d_in[4];
  const float* W2_w    = (const float*)d_in[5];
  const float* W2_b    = (const float*)d_in[6];
  const float* norm_w  = (const float*)d_in[7];
  const float* norm_b  = (const float*)d_in[8];
  const float* head_w  = (const float*)d_in[9];
  const float* head_b  = (const float*)d_in[10];
  (void)in_sizes; (void)n_in; (void)out_size;

  char* ws = (char*)d_ws;
  unsigned short* W1b  = (unsigned short*)(ws);              //  8,388,608  W1 bf16   [4096][1024]
  unsigned short* W2b  = (unsigned short*)(ws + 8388608);    //  8,388,608  W2 bf16   [1024][4096]
  unsigned short* xb   = (unsigned short*)(ws + 16777216);   //  6,553,600  x bf16    [4096][800]
  unsigned short* ewb  = (unsigned short*)(ws + 23330816);   //  1,638,400  embW bf16 [1024][800]
  unsigned short* hwb  = (unsigned short*)(ws + 24969216);   //  2,097,152  headW bf16[1024][1024]
  float*          xemb = (float*)(ws + 27066368);            // 16,777,216  x_emb f32 [4096][1024]
  float*          h    = (float*)(ws + 43843584);            // 16,777,216  h f32     [4096][1024]
  unsigned short* hn   = (unsigned short*)(ws + 60620800);   //  8,388,608  ln(h) bf16[4096][1024]
  unsigned short* act  = (unsigned short*)(ws + 69009408);   // 33,554,432  ffn act   [4096][4096]
  unsigned short* hb   = (unsigned short*)(ws + 102563840);  //  8,388,608  h bf16    [4096][1024]
  unsigned short* P    = (unsigned short*)(ws + 110952448);  // 33,554,432  partials bf16 [4][4096][1024]
  const bool splitk = ws_size >= (size_t)144506880;
  const long PS = 4194304;  // partial stride in u16 elements (4096*1024)

  cvt_pad<<<dim3(4, 4096), 256, 0, stream>>>(W1_w, W1b, 4096, 1024, 1024);
  cvt_pad<<<dim3(16, 1024), 256, 0, stream>>>(W2_w, W2b, 1024, 4096, 4096);
  cvt_pad<<<dim3(4, 4096), 256, 0, stream>>>(x, xb, 4096, 784, 800);
  cvt_pad<<<dim3(4, 1024), 256, 0, stream>>>(embed_w, ewb, 1024, 784, 800);
  cvt_pad<<<dim3(4, 1024), 256, 0, stream>>>(head_w, hwb, 1000, 1024, 1024);

  // x_emb = x @ embed_w^T + embed_b ; h = x_emb
  gemm_bt<0, 128, 128, 64, 64, 3><<<dim3(8, 32), 256, 0, stream>>>(
      xb, ewb, 800, 800, 800, embed_b, 1024, 1024, 8, 4, 4, xemb, h, nullptr, nullptr);

  for (int s = 0; s < 30; s++) {
    if (splitk && s > 0)
      ln_bf16<1><<<4096, 256, 0, stream>>>(h, norm_w, norm_b, hn, xemb, W2_b, P, PS);
    else
      ln_bf16<0><<<4096, 256, 0, stream>>>(h, norm_w, norm_b, hn, nullptr, nullptr, nullptr, 0);

    // act = tanh(hn @ W1^T + b1): proven 2-phase 128^2, 1024 blocks, packed store
    gemm_bt<1, 128, 128, 64, 64, 3><<<dim3(32, 32), 256, 0, stream>>>(
        hn, W1b, 1024, 1024, 1024, W1_b, 4096, 4096, 8, 4, 16, nullptr, nullptr, act, nullptr);

    if (splitk) {
      // P[z] = act[:, z*1024:+1024] @ W2^T chunk (bf16, packed store):
      // grid m32 x n8 x z4 = 1024 blocks; per-z shape == G1's proven shape
      gemm_bt<4, 128, 128, 64, 64, 3><<<dim3(8, 32, 4), 256, 0, stream>>>(
          act, W2b, 1024, 4096, 4096, nullptr, 1024, (int)PS, 8, 4, 4,
          nullptr, nullptr, P, nullptr);
    } else {
      // fallback: h = .5h + .5(act @ W2^T + b2 + xemb) direct RMW
      gemm_bt<2, 128, 64, 64, 32, 4><<<dim3(16, 32), 256, 0, stream>>>(
          act, W2b, 4096, 4096, 4096, W2_b, 1024, 1024, 8, 4, 8, h, nullptr, nullptr, xemb);
    }
  }

  if (splitk)
    cvt_h<1><<<4096, 256, 0, stream>>>(h, hb, xemb, W2_b, P, PS);
  else
    cvt_h<0><<<4096, 256, 0, stream>>>(h, hb, nullptr, nullptr, nullptr, 0);

  gemm_bt<3, 128, 128, 64, 64, 3><<<dim3(8, 32), 256, 0, stream>>>(
      hb, hwb, 1024, 1024, 1024, head_b, 1000, 1000, 8, 4, 4, (float*)d_out, nullptr, nullptr, nullptr);
}